// Round 7
// baseline (166.399 us; speedup 1.0000x reference)
//
#include <hip/hip_runtime.h>
#include <math.h>

#define NN 384
#define NSQ (NN*NN)          // 147456

// workspace float offsets
#define WS_MASKF 0           // 384
#define WS_C1    384         // 384*8   = 3072
#define WS_P     3456        // 384*512 = 196608
#define WS_VN    200064      // 384*256 = 98304
#define WS_T     298368      // (unused after fusion; kept for layout stability)
#define WS_GH    494976      // 64*384  = 24576
#define WS_WT    519552      // 64*64 bf16 (2048 floats used)  WtBF[o][c] = We[o,256+c]
#define WS_WOT   523648      // 256*128 = 32768  Wo^T            [dd][o]
#define WS_WVE   556416      // 64*256  = 16384  Wv[:,128:192]^T [c][d]
#define WS_WEN   572800      // 256*64  = 16384  We[:,0:256]^T   [dd][o]
#define WS_EB    589184      // bf16 staged edges eB[i][j][c]: 64*384*384 shorts
                             // = 4718592 floats; ws ends ~21.2 MB < 256 MiB
typedef short short8 __attribute__((ext_vector_type(8)));
typedef float f32x4 __attribute__((ext_vector_type(4)));

__device__ __forceinline__ unsigned short f2bf(float x) {
    unsigned u = __float_as_uint(x);
    return (unsigned short)((u + 0x7FFFu + ((u >> 16) & 1u)) >> 16);
}

// ---------------------------------------------------------------------------
// K1: projections + c1 + P. Blocks 0..47: 8 columns i each. Block 48: mask.
// Block 49: WtBF (bf16). Blocks 50/51/52: WoT / WvE / WeN transposes.
__global__ __launch_bounds__(256) void k_proj(
    const float* __restrict__ nodes, const float* __restrict__ Wq,
    const float* __restrict__ Wk, const float* __restrict__ Wv,
    const float* __restrict__ Wo, const float* __restrict__ We,
    const unsigned int* __restrict__ mi, float* __restrict__ ws) {
    int tid = threadIdx.x;
    if (blockIdx.x >= 48) {
        if (blockIdx.x == 48) {
            __shared__ int bytemode;
            if (tid == 0) bytemode = 0;
            __syncthreads();
            unsigned v0 = mi[tid];
            unsigned v1 = (tid < 128) ? mi[256 + tid] : 0u;
            if (v0 > 1u || v1 > 1u) bytemode = 1;   // benign race
            __syncthreads();
            float* maskf = ws + WS_MASKF;
            for (int j = tid; j < NN; j += 256) {
                int on;
                if (bytemode) on = (((const unsigned char*)mi)[j] != 0);
                else          on = (mi[j] != 0u);
                maskf[j] = on ? 1.0f : 0.0f;
            }
        } else if (blockIdx.x == 49) {
            // bf16 weight for k_edge's MFMA: WtBF[o][c] = We[o, 256+c]
            unsigned short* WtBF = reinterpret_cast<unsigned short*>(ws + WS_WT);
            for (int idx = tid; idx < 4096; idx += 256) {
                int o = idx >> 6, c = idx & 63;
                WtBF[o * 64 + c] = f2bf(We[o * 320 + 256 + c]);
            }
        } else if (blockIdx.x == 50) {
            float* WoT = ws + WS_WOT;
            for (int idx = tid; idx < 32768; idx += 256) {
                int dd = idx >> 7, o = idx & 127;
                WoT[dd * 128 + o] = Wo[o * 256 + dd];
            }
        } else if (blockIdx.x == 51) {
            float* WvE = ws + WS_WVE;
            for (int idx = tid; idx < 16384; idx += 256) {
                int c = idx >> 8, d = idx & 255;
                WvE[c * 256 + d] = Wv[d * 192 + 128 + c];
            }
        } else {
            float* WeN = ws + WS_WEN;
            for (int idx = tid; idx < 16384; idx += 256) {
                int dd = idx >> 6, o = idx & 63;
                WeN[dd * 64 + o] = We[o * 320 + dd];
            }
        }
        return;
    }
    float* c1_ws = ws + WS_C1;
    float* P_ws  = ws + WS_P;
    float* vn_ws = ws + WS_VN;
    int i0 = blockIdx.x * 8;
    __shared__ float nl[128][8];
    __shared__ float q_l[256][8];
    __shared__ float qk_l[256][8];
    for (int idx = tid; idx < 1024; idx += 256) {
        int m = idx >> 3, ii = idx & 7;
        nl[m][ii] = nodes[m * NN + i0 + ii];
    }
    __syncthreads();
    int o = tid;
    float aq[8], ak[8], av[8];
#pragma unroll
    for (int ii = 0; ii < 8; ii++) { aq[ii] = 0.f; ak[ii] = 0.f; av[ii] = 0.f; }
#pragma unroll 4
    for (int m = 0; m < 128; m++) {
        float wq = Wq[o * 128 + m];
        float wk = Wk[o * 192 + m];
        float wv = Wv[o * 192 + m];
#pragma unroll
        for (int ii = 0; ii < 8; ii++) {
            float nv = nl[m][ii];
            aq[ii] = fmaf(wq, nv, aq[ii]);
            ak[ii] = fmaf(wk, nv, ak[ii]);
            av[ii] = fmaf(wv, nv, av[ii]);
        }
    }
#pragma unroll
    for (int ii = 0; ii < 8; ii++) {
        vn_ws[(size_t)(i0 + ii) * 256 + o] = av[ii];
        q_l[o][ii]  = aq[ii];
        qk_l[o][ii] = aq[ii] * ak[ii];
    }
    __syncthreads();
    if (tid < 64) {
        int h = tid >> 3, ii = tid & 7;
        float s = 0.f;
        for (int a = 0; a < 32; a++) s += qk_l[h * 32 + a][ii];
        c1_ws[(i0 + ii) * 8 + h] = s;
    }
    for (int rep = 0; rep < 2; rep++) {
        int idx = rep * 256 + tid;
        int c = idx & 63, h = idx >> 6;
        float ap[8];
#pragma unroll
        for (int ii = 0; ii < 8; ii++) ap[ii] = 0.f;
        for (int a = 0; a < 32; a++) {
            float w = Wk[(h * 32 + a) * 192 + 128 + c];
#pragma unroll
            for (int ii = 0; ii < 8; ii++)
                ap[ii] = fmaf(q_l[h * 32 + a][ii], w, ap[ii]);
        }
#pragma unroll
        for (int ii = 0; ii < 8; ii++)
            P_ws[(size_t)(i0 + ii) * 512 + c * 8 + h] = ap[ii];
    }
}

// ---------------------------------------------------------------------------
// K2 (FUSED attn + nf): block = row i, 512 threads.
// NEW: pass1 also writes the bf16-converted edge row to eB[i][j][c] (global)
// -- k_edge then reads 18.9MB bf16 contiguous instead of 37.7MB f32 strided.
// Cost here: 8 fire-and-forget 16B stores/thread (~3us BW total).
__global__ __launch_bounds__(512) void k_attn(
    const float* __restrict__ edges, float* __restrict__ ws,
    float* __restrict__ gh_ws, float* __restrict__ out) {
    __shared__ __align__(16) unsigned short epad_h[64 * 392];  // 50176 B
    __shared__ __align__(16) float sT2[NN * 8];                // 12288 B
    __shared__ __align__(16) float T_lds[512];                 // 2048 B
    __shared__ float nf_lds[256];                              // 1024 B
    const float* maskf = ws + WS_MASKF;
    const float* c1w   = ws + WS_C1;
    const float* Pw    = ws + WS_P;
    const float* vn_ws = ws + WS_VN;
    const float* WvE   = ws + WS_WVE;
    const float* WoT   = ws + WS_WOT;
    const float* WeN   = ws + WS_WEN;
    unsigned short* eB = reinterpret_cast<unsigned short*>(ws + WS_EB);
    int i = blockIdx.x;
    int tid = threadIdx.x;
    int wv = tid >> 6, ln = tid & 63;
    float mask_i = maskf[i];

    if (tid < NN) {
        int j = tid;
        const float* eb = edges + (size_t)i * NN + j;
        const float* Pi = Pw + (size_t)i * 512;
        unsigned short* eBp = eB + ((size_t)i * NN + j) * 64;
        float acc[8];
#pragma unroll
        for (int h = 0; h < 8; h++) acc[h] = 0.f;
#pragma unroll
        for (int cb = 0; cb < 4; cb++) {
            float ev[16];
#pragma unroll
            for (int t = 0; t < 16; t++)
                ev[t] = eb[(size_t)(cb * 16 + t) * NSQ];
            short8 p0, p1;
#pragma unroll
            for (int t = 0; t < 8; t++) {
                unsigned short b = f2bf(ev[t]);
                p0[t] = (short)b;
                epad_h[(cb * 16 + t) * 392 + j] = b;
            }
#pragma unroll
            for (int t = 0; t < 8; t++) {
                unsigned short b = f2bf(ev[t + 8]);
                p1[t] = (short)b;
                epad_h[(cb * 16 + 8 + t) * 392 + j] = b;
            }
            *reinterpret_cast<short8*>(&eBp[cb * 16])     = p0;
            *reinterpret_cast<short8*>(&eBp[cb * 16 + 8]) = p1;
#pragma unroll
            for (int t = 0; t < 16; t++) {
                const float* Pc = Pi + (cb * 16 + t) * 8;   // wave-uniform
#pragma unroll
                for (int h = 0; h < 8; h++) acc[h] = fmaf(Pc[h], ev[t], acc[h]);
            }
        }
        float mj = maskf[j];
        const float* c1i = c1w + i * 8;
        float sv[8];
#pragma unroll
        for (int h = 0; h < 8; h++) {
            float s = (c1i[h] + acc[h]) * 0.17677669529663687f;
            sv[h] = (mj != 0.0f) ? s : -1e30f;
        }
        *reinterpret_cast<float4*>(&sT2[j * 8])     = make_float4(sv[0], sv[1], sv[2], sv[3]);
        *reinterpret_cast<float4*>(&sT2[j * 8 + 4]) = make_float4(sv[4], sv[5], sv[6], sv[7]);
    }
    __syncthreads();
    // softmax: wave wv owns head h=wv, lanes cover j = ln + 64k
    float v[6];
    {
        int h = wv;
#pragma unroll
        for (int k = 0; k < 6; k++) v[k] = sT2[(ln + 64 * k) * 8 + h];
    }
    __syncthreads();   // all sT2 reads done; safe to overlay s_bf below
    {
        int h = wv;
        float m = v[0];
#pragma unroll
        for (int k = 1; k < 6; k++) m = fmaxf(m, v[k]);
#pragma unroll
        for (int s = 1; s < 64; s <<= 1) m = fmaxf(m, __shfl_xor(m, s));
        float ex[6]; float sum = 0.f;
#pragma unroll
        for (int k = 0; k < 6; k++) { ex[k] = __expf(v[k] - m); sum += ex[k]; }
#pragma unroll
        for (int s = 1; s < 64; s <<= 1) sum += __shfl_xor(sum, s);
        float fac = mask_i / sum;
        unsigned short* s_bf = reinterpret_cast<unsigned short*>(sT2);
#pragma unroll
        for (int k = 0; k < 6; k++)
            s_bf[h * 392 + ln + 64 * k] = f2bf(ex[k] * fac);
    }
    __syncthreads();
    // pass2: 4-wave MFMA. Wave wv (0..3) owns c-tile wv; 12 MFMAs each.
    if (tid < 256) {
        const unsigned short* s_bf = reinterpret_cast<const unsigned short*>(sT2);
        int nc   = ln & 15;
        int quad = ln >> 4;
        int hrow = nc & 7;
        f32x4 acc = {0.f, 0.f, 0.f, 0.f};
#pragma unroll
        for (int s = 0; s < 12; s++) {
            int jb = s * 32 + quad * 8;
            short8 a = *reinterpret_cast<const short8*>(&s_bf[hrow * 392 + jb]);
            short8 b = *reinterpret_cast<const short8*>(&epad_h[(wv * 16 + nc) * 392 + jb]);
            acc = __builtin_amdgcn_mfma_f32_16x16x32_bf16(a, b, acc, 0, 0, 0);
        }
        if (ln < 32) {   // quads 0,1 -> D rows 0..7 (valid h)
#pragma unroll
            for (int r = 0; r < 4; r++) {
                int h = quad * 4 + r;
                T_lds[h * 64 + wv * 16 + nc] = acc[r];
            }
        }
    }
    __syncthreads();
    // tail #1 (was k_nf phase 1): nf[d] = mask_i*vn[i,d] + WvE^T @ T
    if (tid < 256) {
        int d = tid, h = d >> 5;
        float a0 = 0.f, a1 = 0.f, a2 = 0.f, a3 = 0.f;
#pragma unroll
        for (int c = 0; c < 64; c += 4) {
            a0 = fmaf(WvE[(c    ) * 256 + d], T_lds[h * 64 + c    ], a0);
            a1 = fmaf(WvE[(c + 1) * 256 + d], T_lds[h * 64 + c + 1], a1);
            a2 = fmaf(WvE[(c + 2) * 256 + d], T_lds[h * 64 + c + 2], a2);
            a3 = fmaf(WvE[(c + 3) * 256 + d], T_lds[h * 64 + c + 3], a3);
        }
        nf_lds[d] = mask_i * vn_ws[(size_t)i * 256 + d] + ((a0 + a1) + (a2 + a3));
    }
    __syncthreads();
    // tail #2: node_out = Wo@nf ; gh = 0.5 * WeN@nf
    if (tid < 128) {
        int o = tid;
        float b0 = 0.f, b1 = 0.f, b2 = 0.f, b3 = 0.f;
#pragma unroll 8
        for (int dd = 0; dd < 256; dd += 4) {
            b0 = fmaf(WoT[(dd    ) * 128 + o], nf_lds[dd    ], b0);
            b1 = fmaf(WoT[(dd + 1) * 128 + o], nf_lds[dd + 1], b1);
            b2 = fmaf(WoT[(dd + 2) * 128 + o], nf_lds[dd + 2], b2);
            b3 = fmaf(WoT[(dd + 3) * 128 + o], nf_lds[dd + 3], b3);
        }
        out[o * NN + i] = (b0 + b1) + (b2 + b3);
    } else if (tid < 192) {
        int o = tid - 128;
        float b0 = 0.f, b1 = 0.f, b2 = 0.f, b3 = 0.f;
#pragma unroll 8
        for (int dd = 0; dd < 256; dd += 4) {
            b0 = fmaf(WeN[(dd    ) * 64 + o], nf_lds[dd    ], b0);
            b1 = fmaf(WeN[(dd + 1) * 64 + o], nf_lds[dd + 1], b1);
            b2 = fmaf(WeN[(dd + 2) * 64 + o], nf_lds[dd + 2], b2);
            b3 = fmaf(WeN[(dd + 3) * 64 + o], nf_lds[dd + 3], b3);
        }
        gh_ws[o * NN + i] = 0.5f * ((b0 + b1) + (b2 + b3));
    }
}

// ---------------------------------------------------------------------------
// K4: out_e[o,i,j] = gh[o,i]+gh[o,j]+sum_c WtBF[o][c]*e[c,i,j]   via MFMA.
// phase1 NOW reads the bf16 eB[i][j][c] staged by k_attn: per thread 4x16B
// CONTIGUOUS loads + 4 LDS b128 copies (was 32 loads at 590KB stride + f2bf
// conversion). Fetch halves (18.9MB); the latency-exposed strided gather is
// gone. Grid (384 i, 4 jh) x 192 thr, 6 blocks/CU.
__global__ __launch_bounds__(192) void k_edge(
    const unsigned short* __restrict__ eB, const float* __restrict__ ws_ro,
    float* __restrict__ out_e) {
    __shared__ __align__(16) unsigned short eT[96 * 72];  // [j_loc][c], 13824 B
    const unsigned short* WtBF = reinterpret_cast<const unsigned short*>(ws_ro + WS_WT);
    const float* gh = ws_ro + WS_GH;
    int i = blockIdx.x, jh = blockIdx.y, tid = threadIdx.x;

    // phase1: thread t copies 64B: row jl = t>>1, c-half = (t&1)*32.
    {
        int jl = tid >> 1, half = tid & 1;
        const short8* src = reinterpret_cast<const short8*>(
            eB + ((size_t)i * NN + jh * 96 + jl) * 64 + half * 32);
        short8 v0 = src[0], v1 = src[1], v2 = src[2], v3 = src[3];
        short8* dst = reinterpret_cast<short8*>(&eT[jl * 72 + half * 32]);
        dst[0] = v0; dst[1] = v1; dst[2] = v2; dst[3] = v3;
    }
    __syncthreads();

    // phase2: 3 waves; wave wv owns j-tiles {wv*2, wv*2+1}; all 4 o-tiles.
    int L = tid & 63, wv = tid >> 6;
    int nc = L & 15, quad = L >> 4;
    short8 a00 = *reinterpret_cast<const short8*>(&WtBF[(0 * 16 + nc) * 64 + 0  + quad * 8]);
    short8 a01 = *reinterpret_cast<const short8*>(&WtBF[(0 * 16 + nc) * 64 + 32 + quad * 8]);
    short8 a10 = *reinterpret_cast<const short8*>(&WtBF[(1 * 16 + nc) * 64 + 0  + quad * 8]);
    short8 a11 = *reinterpret_cast<const short8*>(&WtBF[(1 * 16 + nc) * 64 + 32 + quad * 8]);
    short8 a20 = *reinterpret_cast<const short8*>(&WtBF[(2 * 16 + nc) * 64 + 0  + quad * 8]);
    short8 a21 = *reinterpret_cast<const short8*>(&WtBF[(2 * 16 + nc) * 64 + 32 + quad * 8]);
    short8 a30 = *reinterpret_cast<const short8*>(&WtBF[(3 * 16 + nc) * 64 + 0  + quad * 8]);
    short8 a31 = *reinterpret_cast<const short8*>(&WtBF[(3 * 16 + nc) * 64 + 32 + quad * 8]);
    // gh[o, i]: o = ot*16 + quad*4 + r, uniform within 16-lane group.
    float ghi[16];
#pragma unroll
    for (int ot = 0; ot < 4; ot++)
#pragma unroll
        for (int r = 0; r < 4; r++)
            ghi[ot * 4 + r] = gh[(ot * 16 + quad * 4 + r) * NN + i];

#pragma unroll
    for (int jj = 0; jj < 2; jj++) {
        int jt = wv * 2 + jj;
        short8 b0 = *reinterpret_cast<const short8*>(&eT[(jt * 16 + nc) * 72 + 0  + quad * 8]);
        short8 b1 = *reinterpret_cast<const short8*>(&eT[(jt * 16 + nc) * 72 + 32 + quad * 8]);
        int j = jh * 96 + jt * 16 + nc;
        f32x4 c0 = {0.f, 0.f, 0.f, 0.f};
        f32x4 c1 = {0.f, 0.f, 0.f, 0.f};
        f32x4 c2 = {0.f, 0.f, 0.f, 0.f};
        f32x4 c3 = {0.f, 0.f, 0.f, 0.f};
        c0 = __builtin_amdgcn_mfma_f32_16x16x32_bf16(a00, b0, c0, 0, 0, 0);
        c0 = __builtin_amdgcn_mfma_f32_16x16x32_bf16(a01, b1, c0, 0, 0, 0);
        c1 = __builtin_amdgcn_mfma_f32_16x16x32_bf16(a10, b0, c1, 0, 0, 0);
        c1 = __builtin_amdgcn_mfma_f32_16x16x32_bf16(a11, b1, c1, 0, 0, 0);
        c2 = __builtin_amdgcn_mfma_f32_16x16x32_bf16(a20, b0, c2, 0, 0, 0);
        c2 = __builtin_amdgcn_mfma_f32_16x16x32_bf16(a21, b1, c2, 0, 0, 0);
        c3 = __builtin_amdgcn_mfma_f32_16x16x32_bf16(a30, b0, c3, 0, 0, 0);
        c3 = __builtin_amdgcn_mfma_f32_16x16x32_bf16(a31, b1, c3, 0, 0, 0);
#pragma unroll
        for (int ot = 0; ot < 4; ot++) {
            f32x4 cc = ot == 0 ? c0 : ot == 1 ? c1 : ot == 2 ? c2 : c3;
#pragma unroll
            for (int r = 0; r < 4; r++) {
                int o = ot * 16 + quad * 4 + r;
                float val = cc[r] + ghi[ot * 4 + r] + gh[o * NN + j];
                __builtin_nontemporal_store(val, &out_e[(size_t)o * NSQ + (size_t)i * NN + j]);
            }
        }
    }
}

// ---------------------------------------------------------------------------
extern "C" void kernel_launch(void* const* d_in, const int* in_sizes, int n_in,
                              void* d_out, int out_size, void* d_ws, size_t ws_size,
                              hipStream_t stream) {
    const float* nodes = (const float*)d_in[0];
    const float* edges = (const float*)d_in[1];
    const unsigned int* mask = (const unsigned int*)d_in[2];
    const float* Wq = (const float*)d_in[3];
    const float* Wk = (const float*)d_in[4];
    const float* Wv = (const float*)d_in[5];
    const float* Wo = (const float*)d_in[6];
    const float* We = (const float*)d_in[7];
    float* out = (float*)d_out;
    float* ws  = (float*)d_ws;
    float* out_e = out + 128 * NN;
    const unsigned short* eB = (const unsigned short*)(ws + WS_EB);

    hipLaunchKernelGGL(k_proj, dim3(53), dim3(256), 0, stream,
                       nodes, Wq, Wk, Wv, Wo, We, mask, ws);
    hipLaunchKernelGGL(k_attn, dim3(384), dim3(512), 0, stream,
                       edges, ws, ws + WS_GH, out);
    hipLaunchKernelGGL(k_edge, dim3(384, 4), dim3(192), 0, stream,
                       eB, ws, out_e);
}

// Round 8
// 156.301 us; speedup vs baseline: 1.0646x; 1.0646x over previous
//
#include <hip/hip_runtime.h>
#include <math.h>

#define NN 384
#define NSQ (NN*NN)          // 147456

// workspace float offsets
#define WS_MASKF 0           // 384
#define WS_C1    384         // 384*8   = 3072
#define WS_P     3456        // 384*512 = 196608
#define WS_VN    200064      // 384*256 = 98304
#define WS_T     298368      // (unused after fusion; kept for layout stability)
#define WS_GH    494976      // 64*384  = 24576
#define WS_WT    519552      // 64*64 bf16 (2048 floats used)  WtBF[o][c] = We[o,256+c]
#define WS_WOT   523648      // 256*128 = 32768  Wo^T            [dd][o]
#define WS_WVE   556416      // 64*256  = 16384  Wv[:,128:192]^T [c][d]
#define WS_WEN   572800      // 256*64  = 16384  We[:,0:256]^T   [dd][o]

typedef short short8 __attribute__((ext_vector_type(8)));
typedef float f32x4 __attribute__((ext_vector_type(4)));

__device__ __forceinline__ unsigned short f2bf(float x) {
    unsigned u = __float_as_uint(x);
    return (unsigned short)((u + 0x7FFFu + ((u >> 16) & 1u)) >> 16);
}
__device__ __forceinline__ float bf2f(unsigned short b) {
    return __uint_as_float(((unsigned)b) << 16);
}

// ---------------------------------------------------------------------------
// K1: projections + c1 + P. Blocks 0..47: 8 columns i each. Block 48: mask.
// Block 49: WtBF (bf16). Blocks 50/51/52: WoT / WvE / WeN transposes.
__global__ __launch_bounds__(256) void k_proj(
    const float* __restrict__ nodes, const float* __restrict__ Wq,
    const float* __restrict__ Wk, const float* __restrict__ Wv,
    const float* __restrict__ Wo, const float* __restrict__ We,
    const unsigned int* __restrict__ mi, float* __restrict__ ws) {
    int tid = threadIdx.x;
    if (blockIdx.x >= 48) {
        if (blockIdx.x == 48) {
            __shared__ int bytemode;
            if (tid == 0) bytemode = 0;
            __syncthreads();
            unsigned v0 = mi[tid];
            unsigned v1 = (tid < 128) ? mi[256 + tid] : 0u;
            if (v0 > 1u || v1 > 1u) bytemode = 1;   // benign race
            __syncthreads();
            float* maskf = ws + WS_MASKF;
            for (int j = tid; j < NN; j += 256) {
                int on;
                if (bytemode) on = (((const unsigned char*)mi)[j] != 0);
                else          on = (mi[j] != 0u);
                maskf[j] = on ? 1.0f : 0.0f;
            }
        } else if (blockIdx.x == 49) {
            // bf16 weight for k_edge's MFMA: WtBF[o][c] = We[o, 256+c]
            unsigned short* WtBF = reinterpret_cast<unsigned short*>(ws + WS_WT);
            for (int idx = tid; idx < 4096; idx += 256) {
                int o = idx >> 6, c = idx & 63;
                WtBF[o * 64 + c] = f2bf(We[o * 320 + 256 + c]);
            }
        } else if (blockIdx.x == 50) {
            float* WoT = ws + WS_WOT;
            for (int idx = tid; idx < 32768; idx += 256) {
                int dd = idx >> 7, o = idx & 127;
                WoT[dd * 128 + o] = Wo[o * 256 + dd];
            }
        } else if (blockIdx.x == 51) {
            float* WvE = ws + WS_WVE;
            for (int idx = tid; idx < 16384; idx += 256) {
                int c = idx >> 8, d = idx & 255;
                WvE[c * 256 + d] = Wv[d * 192 + 128 + c];
            }
        } else {
            float* WeN = ws + WS_WEN;
            for (int idx = tid; idx < 16384; idx += 256) {
                int dd = idx >> 6, o = idx & 63;
                WeN[dd * 64 + o] = We[o * 320 + dd];
            }
        }
        return;
    }
    float* c1_ws = ws + WS_C1;
    float* P_ws  = ws + WS_P;
    float* vn_ws = ws + WS_VN;
    int i0 = blockIdx.x * 8;
    __shared__ float nl[128][8];
    __shared__ float q_l[256][8];
    __shared__ float qk_l[256][8];
    for (int idx = tid; idx < 1024; idx += 256) {
        int m = idx >> 3, ii = idx & 7;
        nl[m][ii] = nodes[m * NN + i0 + ii];
    }
    __syncthreads();
    int o = tid;
    float aq[8], ak[8], av[8];
#pragma unroll
    for (int ii = 0; ii < 8; ii++) { aq[ii] = 0.f; ak[ii] = 0.f; av[ii] = 0.f; }
#pragma unroll 4
    for (int m = 0; m < 128; m++) {
        float wq = Wq[o * 128 + m];
        float wk = Wk[o * 192 + m];
        float wv = Wv[o * 192 + m];
#pragma unroll
        for (int ii = 0; ii < 8; ii++) {
            float nv = nl[m][ii];
            aq[ii] = fmaf(wq, nv, aq[ii]);
            ak[ii] = fmaf(wk, nv, ak[ii]);
            av[ii] = fmaf(wv, nv, av[ii]);
        }
    }
#pragma unroll
    for (int ii = 0; ii < 8; ii++) {
        vn_ws[(size_t)(i0 + ii) * 256 + o] = av[ii];
        q_l[o][ii]  = aq[ii];
        qk_l[o][ii] = aq[ii] * ak[ii];
    }
    __syncthreads();
    if (tid < 64) {
        int h = tid >> 3, ii = tid & 7;
        float s = 0.f;
        for (int a = 0; a < 32; a++) s += qk_l[h * 32 + a][ii];
        c1_ws[(i0 + ii) * 8 + h] = s;
    }
    for (int rep = 0; rep < 2; rep++) {
        int idx = rep * 256 + tid;
        int c = idx & 63, h = idx >> 6;
        float ap[8];
#pragma unroll
        for (int ii = 0; ii < 8; ii++) ap[ii] = 0.f;
        for (int a = 0; a < 32; a++) {
            float w = Wk[(h * 32 + a) * 192 + 128 + c];
#pragma unroll
            for (int ii = 0; ii < 8; ii++)
                ap[ii] = fmaf(q_l[h * 32 + a][ii], w, ap[ii]);
        }
#pragma unroll
        for (int ii = 0; ii < 8; ii++)
            P_ws[(size_t)(i0 + ii) * 512 + c * 8 + h] = ap[ii];
    }
}

// ---------------------------------------------------------------------------
// K2 (FUSED attn + nf): block = row i, 512 threads.
// RESTRUCTURED pass1 (round-7 counters: 41.7us, VALUBusy 8%, 0.5 TB/s read
// -- the per-thread 64-row strided gather was latency-bound):
//   stage: ALL 512 threads, thread=(c, j-chunk): 12 CONTIGUOUS float4 loads
//     (192B run) -> bf16 -> LDS [c][392]. Coalesced; 512 threads of loads
//     in flight instead of 384 threads x strided bursts.
//   sim: thread=j reads e back from LDS (ds_read_u16, 2-way-free banks),
//     P via wave-uniform s_load. sim now uses bf16-rounded e (was f32) --
//     value path was already bf16; accepted numeric drift.
// eB handoff REVERTED (round-7: regressed, stores serialized into pass1).
__global__ __launch_bounds__(512) void k_attn(
    const float* __restrict__ edges, const float* __restrict__ ws_ro,
    float* __restrict__ gh_ws, float* __restrict__ out) {
    __shared__ __align__(16) unsigned short epad_h[64 * 392];  // 50176 B
    __shared__ __align__(16) float sT2[NN * 8];                // 12288 B
    __shared__ __align__(16) float T_lds[512];                 // 2048 B
    __shared__ float nf_lds[256];                              // 1024 B
    const float* maskf = ws_ro + WS_MASKF;
    const float* c1w   = ws_ro + WS_C1;
    const float* Pw    = ws_ro + WS_P;
    const float* vn_ws = ws_ro + WS_VN;
    const float* WvE   = ws_ro + WS_WVE;
    const float* WoT   = ws_ro + WS_WOT;
    const float* WeN   = ws_ro + WS_WEN;
    int i = blockIdx.x;
    int tid = threadIdx.x;
    int wv = tid >> 6, ln = tid & 63;
    float mask_i = maskf[i];

    // stage: thread (c = tid>>3, g = tid&7) loads e[c, i, g*48 .. g*48+47]
    {
        int c = tid >> 3, g = tid & 7;
        const float* src = edges + (size_t)c * NSQ + (size_t)i * NN + g * 48;
        float4 v0  = reinterpret_cast<const float4*>(src)[0];
        float4 v1  = reinterpret_cast<const float4*>(src)[1];
        float4 v2  = reinterpret_cast<const float4*>(src)[2];
        float4 v3  = reinterpret_cast<const float4*>(src)[3];
        float4 v4  = reinterpret_cast<const float4*>(src)[4];
        float4 v5  = reinterpret_cast<const float4*>(src)[5];
        float4 v6  = reinterpret_cast<const float4*>(src)[6];
        float4 v7  = reinterpret_cast<const float4*>(src)[7];
        float4 v8  = reinterpret_cast<const float4*>(src)[8];
        float4 v9  = reinterpret_cast<const float4*>(src)[9];
        float4 v10 = reinterpret_cast<const float4*>(src)[10];
        float4 v11 = reinterpret_cast<const float4*>(src)[11];
        unsigned short* dst = &epad_h[c * 392 + g * 48];
#define PACK2(A, B, OFS)                                                     \
        {                                                                    \
            short8 p;                                                        \
            p[0] = (short)f2bf(A.x); p[1] = (short)f2bf(A.y);                \
            p[2] = (short)f2bf(A.z); p[3] = (short)f2bf(A.w);                \
            p[4] = (short)f2bf(B.x); p[5] = (short)f2bf(B.y);                \
            p[6] = (short)f2bf(B.z); p[7] = (short)f2bf(B.w);                \
            *reinterpret_cast<short8*>(dst + (OFS)) = p;                     \
        }
        PACK2(v0,  v1,  0)
        PACK2(v2,  v3,  8)
        PACK2(v4,  v5,  16)
        PACK2(v6,  v7,  24)
        PACK2(v8,  v9,  32)
        PACK2(v10, v11, 40)
#undef PACK2
    }
    __syncthreads();

    // sim: thread j accumulates over c from LDS
    if (tid < NN) {
        int j = tid;
        const float* Pi = Pw + (size_t)i * 512;
        float acc[8];
#pragma unroll
        for (int h = 0; h < 8; h++) acc[h] = 0.f;
#pragma unroll 8
        for (int c = 0; c < 64; c++) {
            float ev = bf2f(epad_h[c * 392 + j]);
            const float* Pc = Pi + c * 8;     // wave-uniform -> s_load
#pragma unroll
            for (int h = 0; h < 8; h++) acc[h] = fmaf(Pc[h], ev, acc[h]);
        }
        float mj = maskf[j];
        const float* c1i = c1w + i * 8;
        float sv[8];
#pragma unroll
        for (int h = 0; h < 8; h++) {
            float s = (c1i[h] + acc[h]) * 0.17677669529663687f;
            sv[h] = (mj != 0.0f) ? s : -1e30f;
        }
        *reinterpret_cast<float4*>(&sT2[j * 8])     = make_float4(sv[0], sv[1], sv[2], sv[3]);
        *reinterpret_cast<float4*>(&sT2[j * 8 + 4]) = make_float4(sv[4], sv[5], sv[6], sv[7]);
    }
    __syncthreads();
    // softmax: wave wv owns head h=wv, lanes cover j = ln + 64k
    float v[6];
    {
        int h = wv;
#pragma unroll
        for (int k = 0; k < 6; k++) v[k] = sT2[(ln + 64 * k) * 8 + h];
    }
    __syncthreads();   // all sT2 reads done; safe to overlay s_bf below
    {
        int h = wv;
        float m = v[0];
#pragma unroll
        for (int k = 1; k < 6; k++) m = fmaxf(m, v[k]);
#pragma unroll
        for (int s = 1; s < 64; s <<= 1) m = fmaxf(m, __shfl_xor(m, s));
        float ex[6]; float sum = 0.f;
#pragma unroll
        for (int k = 0; k < 6; k++) { ex[k] = __expf(v[k] - m); sum += ex[k]; }
#pragma unroll
        for (int s = 1; s < 64; s <<= 1) sum += __shfl_xor(sum, s);
        float fac = mask_i / sum;
        unsigned short* s_bf = reinterpret_cast<unsigned short*>(sT2);
#pragma unroll
        for (int k = 0; k < 6; k++)
            s_bf[h * 392 + ln + 64 * k] = f2bf(ex[k] * fac);
    }
    __syncthreads();
    // pass2: 4-wave MFMA. Wave wv (0..3) owns c-tile wv; 12 MFMAs each.
    if (tid < 256) {
        const unsigned short* s_bf = reinterpret_cast<const unsigned short*>(sT2);
        int nc   = ln & 15;
        int quad = ln >> 4;
        int hrow = nc & 7;
        f32x4 acc = {0.f, 0.f, 0.f, 0.f};
#pragma unroll
        for (int s = 0; s < 12; s++) {
            int jb = s * 32 + quad * 8;
            short8 a = *reinterpret_cast<const short8*>(&s_bf[hrow * 392 + jb]);
            short8 b = *reinterpret_cast<const short8*>(&epad_h[(wv * 16 + nc) * 392 + jb]);
            acc = __builtin_amdgcn_mfma_f32_16x16x32_bf16(a, b, acc, 0, 0, 0);
        }
        if (ln < 32) {   // quads 0,1 -> D rows 0..7 (valid h)
#pragma unroll
            for (int r = 0; r < 4; r++) {
                int h = quad * 4 + r;
                T_lds[h * 64 + wv * 16 + nc] = acc[r];
            }
        }
    }
    __syncthreads();
    // tail #1 (was k_nf phase 1): nf[d] = mask_i*vn[i,d] + WvE^T @ T
    if (tid < 256) {
        int d = tid, h = d >> 5;
        float a0 = 0.f, a1 = 0.f, a2 = 0.f, a3 = 0.f;
#pragma unroll
        for (int c = 0; c < 64; c += 4) {
            a0 = fmaf(WvE[(c    ) * 256 + d], T_lds[h * 64 + c    ], a0);
            a1 = fmaf(WvE[(c + 1) * 256 + d], T_lds[h * 64 + c + 1], a1);
            a2 = fmaf(WvE[(c + 2) * 256 + d], T_lds[h * 64 + c + 2], a2);
            a3 = fmaf(WvE[(c + 3) * 256 + d], T_lds[h * 64 + c + 3], a3);
        }
        nf_lds[d] = mask_i * vn_ws[(size_t)i * 256 + d] + ((a0 + a1) + (a2 + a3));
    }
    __syncthreads();
    // tail #2: node_out = Wo@nf ; gh = 0.5 * WeN@nf
    if (tid < 128) {
        int o = tid;
        float b0 = 0.f, b1 = 0.f, b2 = 0.f, b3 = 0.f;
#pragma unroll 8
        for (int dd = 0; dd < 256; dd += 4) {
            b0 = fmaf(WoT[(dd    ) * 128 + o], nf_lds[dd    ], b0);
            b1 = fmaf(WoT[(dd + 1) * 128 + o], nf_lds[dd + 1], b1);
            b2 = fmaf(WoT[(dd + 2) * 128 + o], nf_lds[dd + 2], b2);
            b3 = fmaf(WoT[(dd + 3) * 128 + o], nf_lds[dd + 3], b3);
        }
        out[o * NN + i] = (b0 + b1) + (b2 + b3);
    } else if (tid < 192) {
        int o = tid - 128;
        float b0 = 0.f, b1 = 0.f, b2 = 0.f, b3 = 0.f;
#pragma unroll 8
        for (int dd = 0; dd < 256; dd += 4) {
            b0 = fmaf(WeN[(dd    ) * 64 + o], nf_lds[dd    ], b0);
            b1 = fmaf(WeN[(dd + 1) * 64 + o], nf_lds[dd + 1], b1);
            b2 = fmaf(WeN[(dd + 2) * 64 + o], nf_lds[dd + 2], b2);
            b3 = fmaf(WeN[(dd + 3) * 64 + o], nf_lds[dd + 3], b3);
        }
        gh_ws[o * NN + i] = 0.5f * ((b0 + b1) + (b2 + b3));
    }
}

// ---------------------------------------------------------------------------
// K4: out_e[o,i,j] = gh[o,i]+gh[o,j]+sum_c WtBF[o][c]*e[c,i,j]   via MFMA.
// phase1 RESTRUCTURED like k_attn: thread=(c = tid/3, g = tid%3) loads 32
// CONTIGUOUS j's (8 float4), converts, scatters 32 u16 into eT[j][c].
// (was: per-thread 32-row strided gather, latency-exposed.) LDS scatter
// traffic tiny; HBM access now contiguous runs. eB handoff reverted.
// Grid (384 i, 4 jh) x 192 thr, 6 blocks/CU.
__global__ __launch_bounds__(192) void k_edge(
    const float* __restrict__ edges, const float* __restrict__ ws_ro,
    float* __restrict__ out_e) {
    __shared__ __align__(16) unsigned short eT[96 * 72];  // [j_loc][c], 13824 B
    const unsigned short* WtBF = reinterpret_cast<const unsigned short*>(ws_ro + WS_WT);
    const float* gh = ws_ro + WS_GH;
    int i = blockIdx.x, jh = blockIdx.y, tid = threadIdx.x;

    // phase1: thread (c, g) loads e[c, i, jh*96 + g*32 .. +31] contiguous.
    {
        int c = tid / 3, g = tid - c * 3;      // c 0..63, g 0..2
        const float* src = edges + (size_t)c * NSQ + (size_t)i * NN + jh * 96 + g * 32;
        float4 v0 = reinterpret_cast<const float4*>(src)[0];
        float4 v1 = reinterpret_cast<const float4*>(src)[1];
        float4 v2 = reinterpret_cast<const float4*>(src)[2];
        float4 v3 = reinterpret_cast<const float4*>(src)[3];
        float4 v4 = reinterpret_cast<const float4*>(src)[4];
        float4 v5 = reinterpret_cast<const float4*>(src)[5];
        float4 v6 = reinterpret_cast<const float4*>(src)[6];
        float4 v7 = reinterpret_cast<const float4*>(src)[7];
        int j0 = g * 32;
#define SCAT4(V, T)                                                          \
        eT[(j0 + (T) * 4 + 0) * 72 + c] = f2bf(V.x);                         \
        eT[(j0 + (T) * 4 + 1) * 72 + c] = f2bf(V.y);                         \
        eT[(j0 + (T) * 4 + 2) * 72 + c] = f2bf(V.z);                         \
        eT[(j0 + (T) * 4 + 3) * 72 + c] = f2bf(V.w);
        SCAT4(v0, 0) SCAT4(v1, 1) SCAT4(v2, 2) SCAT4(v3, 3)
        SCAT4(v4, 4) SCAT4(v5, 5) SCAT4(v6, 6) SCAT4(v7, 7)
#undef SCAT4
    }
    __syncthreads();

    // phase2: 3 waves; wave wv owns j-tiles {wv*2, wv*2+1}; all 4 o-tiles.
    int L = tid & 63, wv = tid >> 6;
    int nc = L & 15, quad = L >> 4;
    short8 a00 = *reinterpret_cast<const short8*>(&WtBF[(0 * 16 + nc) * 64 + 0  + quad * 8]);
    short8 a01 = *reinterpret_cast<const short8*>(&WtBF[(0 * 16 + nc) * 64 + 32 + quad * 8]);
    short8 a10 = *reinterpret_cast<const short8*>(&WtBF[(1 * 16 + nc) * 64 + 0  + quad * 8]);
    short8 a11 = *reinterpret_cast<const short8*>(&WtBF[(1 * 16 + nc) * 64 + 32 + quad * 8]);
    short8 a20 = *reinterpret_cast<const short8*>(&WtBF[(2 * 16 + nc) * 64 + 0  + quad * 8]);
    short8 a21 = *reinterpret_cast<const short8*>(&WtBF[(2 * 16 + nc) * 64 + 32 + quad * 8]);
    short8 a30 = *reinterpret_cast<const short8*>(&WtBF[(3 * 16 + nc) * 64 + 0  + quad * 8]);
    short8 a31 = *reinterpret_cast<const short8*>(&WtBF[(3 * 16 + nc) * 64 + 32 + quad * 8]);
    // gh[o, i]: o = ot*16 + quad*4 + r, uniform within 16-lane group.
    float ghi[16];
#pragma unroll
    for (int ot = 0; ot < 4; ot++)
#pragma unroll
        for (int r = 0; r < 4; r++)
            ghi[ot * 4 + r] = gh[(ot * 16 + quad * 4 + r) * NN + i];

#pragma unroll
    for (int jj = 0; jj < 2; jj++) {
        int jt = wv * 2 + jj;
        short8 b0 = *reinterpret_cast<const short8*>(&eT[(jt * 16 + nc) * 72 + 0  + quad * 8]);
        short8 b1 = *reinterpret_cast<const short8*>(&eT[(jt * 16 + nc) * 72 + 32 + quad * 8]);
        int j = jh * 96 + jt * 16 + nc;
        f32x4 c0 = {0.f, 0.f, 0.f, 0.f};
        f32x4 c1 = {0.f, 0.f, 0.f, 0.f};
        f32x4 c2 = {0.f, 0.f, 0.f, 0.f};
        f32x4 c3 = {0.f, 0.f, 0.f, 0.f};
        c0 = __builtin_amdgcn_mfma_f32_16x16x32_bf16(a00, b0, c0, 0, 0, 0);
        c0 = __builtin_amdgcn_mfma_f32_16x16x32_bf16(a01, b1, c0, 0, 0, 0);
        c1 = __builtin_amdgcn_mfma_f32_16x16x32_bf16(a10, b0, c1, 0, 0, 0);
        c1 = __builtin_amdgcn_mfma_f32_16x16x32_bf16(a11, b1, c1, 0, 0, 0);
        c2 = __builtin_amdgcn_mfma_f32_16x16x32_bf16(a20, b0, c2, 0, 0, 0);
        c2 = __builtin_amdgcn_mfma_f32_16x16x32_bf16(a21, b1, c2, 0, 0, 0);
        c3 = __builtin_amdgcn_mfma_f32_16x16x32_bf16(a30, b0, c3, 0, 0, 0);
        c3 = __builtin_amdgcn_mfma_f32_16x16x32_bf16(a31, b1, c3, 0, 0, 0);
#pragma unroll
        for (int ot = 0; ot < 4; ot++) {
            f32x4 cc = ot == 0 ? c0 : ot == 1 ? c1 : ot == 2 ? c2 : c3;
#pragma unroll
            for (int r = 0; r < 4; r++) {
                int o = ot * 16 + quad * 4 + r;
                float val = cc[r] + ghi[ot * 4 + r] + gh[o * NN + j];
                __builtin_nontemporal_store(val, &out_e[(size_t)o * NSQ + (size_t)i * NN + j]);
            }
        }
    }
}

// ---------------------------------------------------------------------------
extern "C" void kernel_launch(void* const* d_in, const int* in_sizes, int n_in,
                              void* d_out, int out_size, void* d_ws, size_t ws_size,
                              hipStream_t stream) {
    const float* nodes = (const float*)d_in[0];
    const float* edges = (const float*)d_in[1];
    const unsigned int* mask = (const unsigned int*)d_in[2];
    const float* Wq = (const float*)d_in[3];
    const float* Wk = (const float*)d_in[4];
    const float* Wv = (const float*)d_in[5];
    const float* Wo = (const float*)d_in[6];
    const float* We = (const float*)d_in[7];
    float* out = (float*)d_out;
    float* ws  = (float*)d_ws;
    float* out_e = out + 128 * NN;

    hipLaunchKernelGGL(k_proj, dim3(53), dim3(256), 0, stream,
                       nodes, Wq, Wk, Wv, Wo, We, mask, ws);
    hipLaunchKernelGGL(k_attn, dim3(384), dim3(512), 0, stream,
                       edges, ws, ws + WS_GH, out);
    hipLaunchKernelGGL(k_edge, dim3(384, 4), dim3(192), 0, stream,
                       edges, ws, out_e);
}